// Round 18
// baseline (113.927 us; speedup 1.0000x reference)
//
#include <hip/hip_runtime.h>
#include <hip/hip_bf16.h>

#define BB     64
#define NF4    200000        // NTOT / 4
#define NP     128
#define NH1    256
#define NH2    128
#define NC     32
#define EPSV   1e-5f
#define QTR    50000         // NF4 / 4 quads per k_seg block

typedef float fx4 __attribute__((ext_vector_type(4)));

__device__ __forceinline__ float dot4(fx4 a, fx4 b) {
    return fmaf(a[0], b[0], fmaf(a[1], b[1], fmaf(a[2], b[2], a[3] * b[3])));
}

// ---------------------------------------------------------------------------
// Pure streaming pass: y[b][n4] = dot4(x[b][quad n4], w[quad n4]).
// NO shuffles, NO LDS, NO waits — structurally a fill-with-reads. w/idx
// read ONCE per quad, amortized over 32 batch rows. Straddling quads
// (<=127 of 200K) send their hi-pathway residue via rare direct atomics.
// R18 FIX vs R17: row indexing done on fx4-typed base (R17 mixed float
// and fx4 offsets -> batches 32-63 read rows 8-39).
// ---------------------------------------------------------------------------
__global__ __launch_bounds__(256) void k_stream(
    const float* __restrict__ x, const float* __restrict__ w,
    const int* __restrict__ idx, float* __restrict__ y,
    unsigned char* __restrict__ pq, float* __restrict__ WX)
{
    const int n4 = blockIdx.x * 256 + threadIdx.x;
    if (n4 >= NF4) return;
    const int b0 = blockIdx.y * 32;

    const fx4  wv = reinterpret_cast<const fx4*>(w)[n4];
    const int4 pv = reinterpret_cast<const int4*>(idx)[n4];
    if (blockIdx.y == 0) pq[n4] = (unsigned char)pv.x;

    const fx4* __restrict__ xq = reinterpret_cast<const fx4*>(x);

    if (pv.x == pv.w) {                       // uniform quad (common)
        #pragma unroll 8
        for (int b = 0; b < 32; ++b)
            y[(size_t)(b0 + b) * NF4 + n4] =
                dot4(xq[(size_t)(b0 + b) * NF4 + n4], wv);
    } else {                                  // straddling quad (rare)
        fx4 wLo, wHi;
        wLo[0] = wv[0];                         wHi[0] = (pv.x == pv.w) ? wv[0] : 0.f;
        wLo[1] = (pv.y == pv.x) ? wv[1] : 0.f;  wHi[1] = (pv.y == pv.w) ? wv[1] : 0.f;
        wLo[2] = (pv.z == pv.x) ? wv[2] : 0.f;  wHi[2] = (pv.z == pv.w) ? wv[2] : 0.f;
        wLo[3] = (pv.w == pv.x) ? wv[3] : 0.f;  wHi[3] = wv[3];
        for (int b = 0; b < 32; ++b) {
            const fx4 xv = xq[(size_t)(b0 + b) * NF4 + n4];
            y[(size_t)(b0 + b) * NF4 + n4] = dot4(xv, wLo);
            atomicAdd(&WX[(b0 + b) * NP + pv.w], dot4(xv, wHi));
        }
    }
}

// ---------------------------------------------------------------------------
// Segmented reduce: WX[b][p] += sum of y[b][n4] where pq[n4]==p.
// 256 blocks = (batch b, quarter s). Per-thread run-merge (sorted pq ->
// long uniform runs) + LDS atomics, then <=128 global atomics per block.
// ---------------------------------------------------------------------------
__global__ __launch_bounds__(256) void k_seg(
    const float* __restrict__ y, const unsigned char* __restrict__ pq,
    float* __restrict__ WX)
{
    __shared__ float lwx[NP];
    const int b   = blockIdx.x >> 2;
    const int s   = blockIdx.x & 3;
    const int tid = threadIdx.x;
    if (tid < NP) lwx[tid] = 0.f;
    __syncthreads();

    const fx4*   __restrict__ yq  = reinterpret_cast<const fx4*>(
                                        y + (size_t)b * NF4 + s * QTR);
    const uchar4* __restrict__ pqq = reinterpret_cast<const uchar4*>(pq + s * QTR);

    float acc = 0.f;
    int   curp = -1;
    for (int i = tid; i < QTR / 4; i += 256) {
        const fx4    v  = yq[i];
        const uchar4 pz = pqq[i];
        if (pz.x == pz.w) {
            const float sv = (v[0] + v[1]) + (v[2] + v[3]);
            if ((int)pz.x == curp) {
                acc += sv;
            } else {
                if (curp >= 0) atomicAdd(&lwx[curp], acc);
                curp = pz.x; acc = sv;
            }
        } else {                              // boundary float4 (rare)
            if (curp >= 0) { atomicAdd(&lwx[curp], acc); curp = -1; acc = 0.f; }
            atomicAdd(&lwx[pz.x], v[0]);
            atomicAdd(&lwx[pz.y], v[1]);
            atomicAdd(&lwx[pz.z], v[2]);
            atomicAdd(&lwx[pz.w], v[3]);
        }
    }
    if (curp >= 0) atomicAdd(&lwx[curp], acc);
    __syncthreads();
    if (tid < NP) {
        const float v = lwx[tid];
        if (v != 0.f) atomicAdd(&WX[b * NP + tid], v);
    }
}

// ---------------------------------------------------------------------------
// Zero WX (PMC-visible).
// ---------------------------------------------------------------------------
__global__ void k_zero(float* __restrict__ WX)
{
    const int i = blockIdx.x * 256 + threadIdx.x;
    if (i < BB * NP) WX[i] = 0.f;
}

__device__ __forceinline__ float bn_shfl(float a, float gj, float bj)
{
    float s = a, q = a * a;
    #pragma unroll
    for (int off = 32; off > 0; off >>= 1) {
        s += __shfl_xor(s, off);
        q += __shfl_xor(q, off);
    }
    const float m   = s * (1.f / BB);
    const float var = q * (1.f / BB) - m * m;
    return (a - m) * rsqrtf(var + EPSV) * gj + bj;
}

// ---------------------------------------------------------------------------
// BN0+gate (redundant per block, parallel) + fc1 + ReLU + BN1.
// ---------------------------------------------------------------------------
__global__ __launch_bounds__(256) void k_fc1z(
    const float* __restrict__ WX,   const float* __restrict__ co_w,
    const float* __restrict__ bn0g, const float* __restrict__ bn0b,
    const float* __restrict__ W1,   const float* __restrict__ b1,
    const float* __restrict__ bn1g, const float* __restrict__ bn1b,
    float* __restrict__ Zout, float* __restrict__ h1t)
{
    __shared__ float Zl[NP * 65];    // pad 65: conflict-free write & read
    const int tid  = threadIdx.x;
    const int wv   = tid >> 6;
    const int lane = tid & 63;       // == batch in fc1 stage
    const int blk  = blockIdx.x;

    if (tid < NP) {
        const int p = tid;
        float sum = 0.f, sq = 0.f;
        #pragma unroll 8
        for (int b = 0; b < BB; ++b) {
            const float r = fmaxf(WX[b * NP + p], 0.f);
            sum += r; sq += r * r;
        }
        const float m   = sum * (1.f / BB);
        const float var = sq * (1.f / BB) - m * m;
        const float sc  = rsqrtf(var + EPSV) * bn0g[p];
        const float bt  = bn0b[p];
        const float sig = 1.f / (1.f + expf(-co_w[p]));
        #pragma unroll 8
        for (int b = 0; b < BB; ++b) {
            const float r = fmaxf(WX[b * NP + p], 0.f);
            const float z = ((r - m) * sc + bt) * sig;
            Zl[p * 65 + b] = z;
            if (blk == 0) Zout[b * NP + p] = z;
        }
    }
    __syncthreads();

    const int j = blk * 4 + wv;      // 0..255
    float acc = b1[j];
    #pragma unroll 8
    for (int k = 0; k < NP; ++k)
        acc = fmaf(Zl[k * 65 + lane], W1[k * NH1 + j], acc);
    h1t[j * BB + lane] = bn_shfl(fmaxf(acc, 0.f), bn1g[j], bn1b[j]);
}

// ---------------------------------------------------------------------------
// fc2 + ReLU + BN2 from TRANSPOSED input [K][BB]. One block per column j.
// ---------------------------------------------------------------------------
template <int K, int NOUT>
__global__ void k_fc_bn_t(const float* __restrict__ in_t,  // [K][BB]
                          const float* __restrict__ W,     // [K, NOUT]
                          const float* __restrict__ bias,
                          const float* __restrict__ g,
                          const float* __restrict__ beta,
                          float* __restrict__ out_t)       // [NOUT][BB]
{
    const int j = blockIdx.x;
    const int b = threadIdx.x;  // 0..63
    float acc = bias[j];
    #pragma unroll 8
    for (int k = 0; k < K; ++k)
        acc = fmaf(in_t[k * BB + b], W[k * NOUT + j], acc);
    out_t[j * BB + b] = bn_shfl(fmaxf(acc, 0.f), g[j], beta[j]);
}

// ---------------------------------------------------------------------------
// Final Linear + row softmax from transposed h2 [NH2][BB].
// ---------------------------------------------------------------------------
__global__ void k_head(const float* __restrict__ h2t,  // [NH2][BB]
                       const float* __restrict__ Wo,   // [NH2, NC]
                       const float* __restrict__ bo,
                       float* __restrict__ y)          // [BB, NC]
{
    const int b = blockIdx.x;
    const int c = threadIdx.x;  // 0..31
    float acc = bo[c];
    #pragma unroll 8
    for (int k = 0; k < NH2; ++k)
        acc = fmaf(h2t[k * BB + b], Wo[k * NC + c], acc);
    float mx = acc;
    #pragma unroll
    for (int off = 16; off > 0; off >>= 1)
        mx = fmaxf(mx, __shfl_xor(mx, off));
    const float e = expf(acc - mx);
    float s = e;
    #pragma unroll
    for (int off = 16; off > 0; off >>= 1)
        s += __shfl_xor(s, off);
    y[b * NC + c] = e / s;
}

// ---------------------------------------------------------------------------
extern "C" void kernel_launch(void* const* d_in, const int* in_sizes, int n_in,
                              void* d_out, int out_size, void* d_ws, size_t ws_size,
                              hipStream_t stream)
{
    const float* x    = (const float*)d_in[0];
    const float* w    = (const float*)d_in[1];
    const float* co_w = (const float*)d_in[2];
    const float* bn0g = (const float*)d_in[3];
    const float* bn0b = (const float*)d_in[4];
    const float* W1   = (const float*)d_in[5];
    const float* b1   = (const float*)d_in[6];
    const float* bn1g = (const float*)d_in[7];
    const float* bn1b = (const float*)d_in[8];
    const float* W2   = (const float*)d_in[9];
    const float* b2   = (const float*)d_in[10];
    const float* bn2g = (const float*)d_in[11];
    const float* bn2b = (const float*)d_in[12];
    const float* Wo   = (const float*)d_in[13];
    const float* bo   = (const float*)d_in[14];
    const int*   idx  = (const int*)d_in[15];

    float* out = (float*)d_out;
    float* yo  = out;               // [64, 32]  (output 0)
    float* Z   = out + BB * NC;     // [64, 128] (output 1)

    float* WX  = (float*)d_ws;                    // 8192 f32
    float* h1t = WX + BB * NP;                    // 16384 f32  [j][b]
    float* h2t = h1t + BB * NH1;                  // 8192 f32   [j][b]
    float* y   = h2t + BB * NH2;                  // 64 x 200000 f32 (51.2 MB)
    unsigned char* pq = (unsigned char*)(y + (size_t)BB * NF4);  // 200 KB

    k_zero<<<32, 256, 0, stream>>>(WX);
    dim3 sgrid((NF4 + 255) / 256, 2);
    k_stream<<<sgrid, 256, 0, stream>>>(x, w, idx, y, pq, WX);
    k_seg<<<BB * 4, 256, 0, stream>>>(y, pq, WX);
    k_fc1z<<<64, 256, 0, stream>>>(WX, co_w, bn0g, bn0b,
                                   W1, b1, bn1g, bn1b, Z, h1t);
    k_fc_bn_t<NH1, NH2><<<NH2, BB, 0, stream>>>(h1t, W2, b2, bn2g, bn2b, h2t);
    k_head<<<BB, NC, 0, stream>>>(h2t, Wo, bo, yo);
}

// Round 19
// 94.114 us; speedup vs baseline: 1.2105x; 1.2105x over previous
//
#include <hip/hip_runtime.h>
#include <hip/hip_bf16.h>

#define BB     64
#define NF4    200000        // NTOT / 4
#define NSEG   782           // ceil(NF4 / 256)
#define NP     128
#define NH1    256
#define NH2    128
#define NC     32
#define EPSV   1e-5f

typedef float fx4 __attribute__((ext_vector_type(4)));

__device__ __forceinline__ float dot4(fx4 a, fx4 b) {
    return fmaf(a[0], b[0], fmaf(a[1], b[1], fmaf(a[2], b[2], a[3] * b[3])));
}

// ---------------------------------------------------------------------------
// Scatter-reduce: WX[b, idx[n]] += x[b,n] * w[n]     (idx sorted)
// R16 lean fill-pattern structure + NON-TEMPORAL x loads (nt flag): x is
// 205MB vs 256MB L3 — every replay streams all of x through L3 with
// fill+evict per line. nt bypasses L3 allocation -> pure HBM read stream.
// w/idx stay cached (x32 reuse). This is the cache-bypass ablation.
// ---------------------------------------------------------------------------
__global__ __launch_bounds__(256) void k_scatter(
    const float* __restrict__ x, const float* __restrict__ w,
    const int* __restrict__ idx, float* __restrict__ WX)
{
    const int blk = blockIdx.x;
    const int b   = blk & 31;            // rows b and b+32
    const int seg = blk >> 5;            // 0..781
    const int tid = threadIdx.x;
    const int n4  = seg * 256 + tid;
    const int waveBase = seg * 256 + (tid & ~63);
    if (waveBase >= NF4) return;         // fully-inactive wave (seg 781 tail)
    if (n4 >= NF4) return;               // (unreachable: NF4 % 64 == 0)
    const int lane = tid & 63;

    // Wave-span pathway endpoints (sorted idx -> <=2 pathways per 256-span).
    const int  pLo = idx[waveBase * 4];
    const int  pHi = idx[waveBase * 4 + 255];
    const bool uniform = (pLo == pHi);

    const fx4  wv = reinterpret_cast<const fx4*>(w)[n4];
    const int4 pv = reinterpret_cast<const int4*>(idx)[n4];
    // NON-TEMPORAL: bypass L2/L3 allocation for the single-use x stream.
    const fx4  xA = __builtin_nontemporal_load(
                        reinterpret_cast<const fx4*>(x) + (size_t)b * NF4 + n4);
    const fx4  xB = __builtin_nontemporal_load(
                        reinterpret_cast<const fx4*>(x) + (size_t)(b + 32) * NF4 + n4);

    fx4 wLo;
    wLo[0] = (pv.x == pLo) ? wv[0] : 0.f;
    wLo[1] = (pv.y == pLo) ? wv[1] : 0.f;
    wLo[2] = (pv.z == pLo) ? wv[2] : 0.f;
    wLo[3] = (pv.w == pLo) ? wv[3] : 0.f;

    float aLo = dot4(xA, wLo);
    float bLo = dot4(xB, wLo);
    #pragma unroll
    for (int off = 1; off < 64; off <<= 1) {   // two interleaved chains
        aLo += __shfl_xor(aLo, off);
        bLo += __shfl_xor(bLo, off);
    }

    if (uniform) {
        const float val = (lane == 0) ? aLo : bLo;
        const int   row = (lane == 0) ? b : (b + 32);
        if (lane < 2)                          // ONE atomic instruction
            atomicAdd(&WX[row * NP + pLo], val);
    } else {                                   // boundary wave (~8%)
        fx4 wHi;
        wHi[0] = (pv.x == pHi) ? wv[0] : 0.f;
        wHi[1] = (pv.y == pHi) ? wv[1] : 0.f;
        wHi[2] = (pv.z == pHi) ? wv[2] : 0.f;
        wHi[3] = (pv.w == pHi) ? wv[3] : 0.f;
        float aHi = dot4(xA, wHi);
        float bHi = dot4(xB, wHi);
        #pragma unroll
        for (int off = 1; off < 64; off <<= 1) {
            aHi += __shfl_xor(aHi, off);
            bHi += __shfl_xor(bHi, off);
        }
        const float val = (lane == 0) ? aLo : ((lane == 1) ? bLo
                        : ((lane == 2) ? aHi : bHi));
        const int   row = ((lane & 1) == 0) ? b : (b + 32);
        const int   col = (lane < 2) ? pLo : pHi;
        if (lane < 4)
            atomicAdd(&WX[row * NP + col], val);
    }
}

// ---------------------------------------------------------------------------
// Zero WX (PMC-visible).
// ---------------------------------------------------------------------------
__global__ void k_zero(float* __restrict__ WX)
{
    const int i = blockIdx.x * 256 + threadIdx.x;
    if (i < BB * NP) WX[i] = 0.f;
}

__device__ __forceinline__ float bn_shfl(float a, float gj, float bj)
{
    float s = a, q = a * a;
    #pragma unroll
    for (int off = 32; off > 0; off >>= 1) {
        s += __shfl_xor(s, off);
        q += __shfl_xor(q, off);
    }
    const float m   = s * (1.f / BB);
    const float var = q * (1.f / BB) - m * m;
    return (a - m) * rsqrtf(var + EPSV) * gj + bj;
}

// ---------------------------------------------------------------------------
// BN0+gate (redundant per block, parallel) + fc1 + ReLU + BN1.
// ---------------------------------------------------------------------------
__global__ __launch_bounds__(256) void k_fc1z(
    const float* __restrict__ WX,   const float* __restrict__ co_w,
    const float* __restrict__ bn0g, const float* __restrict__ bn0b,
    const float* __restrict__ W1,   const float* __restrict__ b1,
    const float* __restrict__ bn1g, const float* __restrict__ bn1b,
    float* __restrict__ Zout, float* __restrict__ h1t)
{
    __shared__ float Zl[NP * 65];    // pad 65: conflict-free write & read
    const int tid  = threadIdx.x;
    const int wv   = tid >> 6;
    const int lane = tid & 63;       // == batch in fc1 stage
    const int blk  = blockIdx.x;

    if (tid < NP) {
        const int p = tid;
        float sum = 0.f, sq = 0.f;
        #pragma unroll 8
        for (int b = 0; b < BB; ++b) {
            const float r = fmaxf(WX[b * NP + p], 0.f);
            sum += r; sq += r * r;
        }
        const float m   = sum * (1.f / BB);
        const float var = sq * (1.f / BB) - m * m;
        const float sc  = rsqrtf(var + EPSV) * bn0g[p];
        const float bt  = bn0b[p];
        const float sig = 1.f / (1.f + expf(-co_w[p]));
        #pragma unroll 8
        for (int b = 0; b < BB; ++b) {
            const float r = fmaxf(WX[b * NP + p], 0.f);
            const float z = ((r - m) * sc + bt) * sig;
            Zl[p * 65 + b] = z;
            if (blk == 0) Zout[b * NP + p] = z;
        }
    }
    __syncthreads();

    const int j = blk * 4 + wv;      // 0..255
    float acc = b1[j];
    #pragma unroll 8
    for (int k = 0; k < NP; ++k)
        acc = fmaf(Zl[k * 65 + lane], W1[k * NH1 + j], acc);
    h1t[j * BB + lane] = bn_shfl(fmaxf(acc, 0.f), bn1g[j], bn1b[j]);
}

// ---------------------------------------------------------------------------
// fc2 + ReLU + BN2 from TRANSPOSED input [K][BB]. One block per column j.
// ---------------------------------------------------------------------------
template <int K, int NOUT>
__global__ void k_fc_bn_t(const float* __restrict__ in_t,  // [K][BB]
                          const float* __restrict__ W,     // [K, NOUT]
                          const float* __restrict__ bias,
                          const float* __restrict__ g,
                          const float* __restrict__ beta,
                          float* __restrict__ out_t)       // [NOUT][BB]
{
    const int j = blockIdx.x;
    const int b = threadIdx.x;  // 0..63
    float acc = bias[j];
    #pragma unroll 8
    for (int k = 0; k < K; ++k)
        acc = fmaf(in_t[k * BB + b], W[k * NOUT + j], acc);
    out_t[j * BB + b] = bn_shfl(fmaxf(acc, 0.f), g[j], beta[j]);
}

// ---------------------------------------------------------------------------
// Final Linear + row softmax from transposed h2 [NH2][BB].
// ---------------------------------------------------------------------------
__global__ void k_head(const float* __restrict__ h2t,  // [NH2][BB]
                       const float* __restrict__ Wo,   // [NH2, NC]
                       const float* __restrict__ bo,
                       float* __restrict__ y)          // [BB, NC]
{
    const int b = blockIdx.x;
    const int c = threadIdx.x;  // 0..31
    float acc = bo[c];
    #pragma unroll 8
    for (int k = 0; k < NH2; ++k)
        acc = fmaf(h2t[k * BB + b], Wo[k * NC + c], acc);
    float mx = acc;
    #pragma unroll
    for (int off = 16; off > 0; off >>= 1)
        mx = fmaxf(mx, __shfl_xor(mx, off));
    const float e = expf(acc - mx);
    float s = e;
    #pragma unroll
    for (int off = 16; off > 0; off >>= 1)
        s += __shfl_xor(s, off);
    y[b * NC + c] = e / s;
}

// ---------------------------------------------------------------------------
extern "C" void kernel_launch(void* const* d_in, const int* in_sizes, int n_in,
                              void* d_out, int out_size, void* d_ws, size_t ws_size,
                              hipStream_t stream)
{
    const float* x    = (const float*)d_in[0];
    const float* w    = (const float*)d_in[1];
    const float* co_w = (const float*)d_in[2];
    const float* bn0g = (const float*)d_in[3];
    const float* bn0b = (const float*)d_in[4];
    const float* W1   = (const float*)d_in[5];
    const float* b1   = (const float*)d_in[6];
    const float* bn1g = (const float*)d_in[7];
    const float* bn1b = (const float*)d_in[8];
    const float* W2   = (const float*)d_in[9];
    const float* b2   = (const float*)d_in[10];
    const float* bn2g = (const float*)d_in[11];
    const float* bn2b = (const float*)d_in[12];
    const float* Wo   = (const float*)d_in[13];
    const float* bo   = (const float*)d_in[14];
    const int*   idx  = (const int*)d_in[15];

    float* out = (float*)d_out;
    float* y   = out;               // [64, 32]  (output 0)
    float* Z   = out + BB * NC;     // [64, 128] (output 1)

    float* WX  = (float*)d_ws;          // 8192 f32
    float* h1t = WX + BB * NP;          // 16384 f32  [j][b]
    float* h2t = h1t + BB * NH1;        // 8192 f32   [j][b]

    k_zero<<<32, 256, 0, stream>>>(WX);
    k_scatter<<<NSEG * 32, 256, 0, stream>>>(x, w, idx, WX);
    k_fc1z<<<64, 256, 0, stream>>>(WX, co_w, bn0g, bn0b,
                                   W1, b1, bn1g, bn1b, Z, h1t);
    k_fc_bn_t<NH1, NH2><<<NH2, BB, 0, stream>>>(h1t, W2, b2, bn2g, bn2b, h2t);
    k_head<<<BB, NC, 0, stream>>>(h2t, Wo, bo, y);
}